// Round 1
// baseline (468.044 us; speedup 1.0000x reference)
//
#include <hip/hip_runtime.h>

#define TSEQ 256
#define FIN  32
#define HID  64

typedef _Float16 f16x8 __attribute__((ext_vector_type(8)));
typedef float    f32x4 __attribute__((ext_vector_type(4)));

__device__ __forceinline__ float sigm(float x) {
    return __builtin_amdgcn_rcpf(1.0f + __expf(-x));
}
__device__ __forceinline__ float tanh_fast(float x) {
    float e = __expf(2.0f * x);
    return 1.0f - 2.0f * __builtin_amdgcn_rcpf(e + 1.0f);
}
__device__ __forceinline__ float wsum(float v) {
    #pragma unroll
    for (int off = 32; off > 0; off >>= 1) v += __shfl_xor(v, off, 64);
    return v;
}

// One block = 16 batch rows for the whole sequence, both LSTM layers fused.
// 512 threads = 8 waves; wave w owns permuted gate slice n' in [w*32, w*32+32).
// Gate permutation: n' = 4*d + type  (type 0..3 = i,f,g,o; d = hidden dim).
__global__ __launch_bounds__(512, 2)
void lstm_fused(const float* __restrict__ x,
                const float* __restrict__ w_ih0, const float* __restrict__ w_hh0,
                const float* __restrict__ b_ih0, const float* __restrict__ b_hh0,
                const float* __restrict__ w_ih1, const float* __restrict__ w_hh1,
                const float* __restrict__ b_ih1, const float* __restrict__ b_hh1,
                const float* __restrict__ ln_g, const float* __restrict__ ln_b,
                const float* __restrict__ w1, const float* __restrict__ b1,
                const float* __restrict__ w2, const float* __restrict__ b2,
                float* __restrict__ out)
{
    // A0 row m: [ x_t (32) | h0 parity0 (64) | h0 parity1 (64) | pad 8 ]
    // A1 row m: [ h0_t (64) | h1 parity0 (64) | h1 parity1 (64) | pad 8 ]
    __shared__ __align__(16) _Float16 A0[16][168];
    __shared__ __align__(16) _Float16 A1[16][200];
    __shared__ __align__(16) float SCR[8][16][36];  // per-wave gate transpose scratch
    __shared__ __align__(16) float HF[16][68];      // final-layer h1 (fp32) for head
    __shared__ __align__(16) float LNB[8][64];      // per-wave layernorm row buffer

    const int tid  = threadIdx.x;
    const int wave = tid >> 6;
    const int lane = tid & 63;
    const int q    = lane >> 4;   // quad-of-16 index (0..3)
    const int lm   = lane & 15;   // m row / n-within-tile
    const int b0   = blockIdx.x * 16;

    // ---- load weight B-fragments into registers (held for the whole kernel) ----
    // B-frag layout for mfma_f32_16x16x32: lane holds B[k = q*8+j][n = lm]
    // B[k][n'] = W_orig[type*64+d][k], n' = wave*32 + tt*16 + lm.
    f16x8 bw0[2][3];   // L0: slice0 = w_ih0 (k=0..31), slice1/2 = w_hh0 (k=0..31 / 32..63)
    f16x8 bw1[2][4];   // L1: slice0/1 = w_ih1, slice2/3 = w_hh1
    float bias0[2], bias1[2];

    #pragma unroll
    for (int tt = 0; tt < 2; ++tt) {
        const int np  = wave * 32 + tt * 16 + lm;
        const int d   = np >> 2;
        const int ty  = np & 3;
        const int row = ty * 64 + d;     // original PyTorch gate-row index
        {
            const float* p = w_ih0 + row * FIN + q * 8;
            #pragma unroll
            for (int j = 0; j < 8; ++j) bw0[tt][0][j] = (_Float16)p[j];
        }
        #pragma unroll
        for (int s = 0; s < 2; ++s) {
            const float* p = w_hh0 + row * HID + s * 32 + q * 8;
            #pragma unroll
            for (int j = 0; j < 8; ++j) bw0[tt][1 + s][j] = (_Float16)p[j];
        }
        #pragma unroll
        for (int s = 0; s < 2; ++s) {
            const float* p = w_ih1 + row * HID + s * 32 + q * 8;
            #pragma unroll
            for (int j = 0; j < 8; ++j) bw1[tt][s][j] = (_Float16)p[j];
        }
        #pragma unroll
        for (int s = 0; s < 2; ++s) {
            const float* p = w_hh1 + row * HID + s * 32 + q * 8;
            #pragma unroll
            for (int j = 0; j < 8; ++j) bw1[tt][2 + s][j] = (_Float16)p[j];
        }
        bias0[tt] = b_ih0[row] + b_hh0[row];
        bias1[tt] = b_ih1[row] + b_hh1[row];
    }

    // ---- zero LDS state ----
    for (int i = tid; i < 16 * 168; i += 512) ((_Float16*)A0)[i] = (_Float16)0.0f;
    for (int i = tid; i < 16 * 200; i += 512) ((_Float16*)A1)[i] = (_Float16)0.0f;
    __syncthreads();

    // ---- stage x for t=0 ----
    const int xrow = tid >> 5, xcol = tid & 31;
    const float* xbase = x + (size_t)(b0 + xrow) * TSEQ * FIN + xcol;
    A0[xrow][xcol] = (_Float16)xbase[0];

    float c0[2] = {0.0f, 0.0f}, c1[2] = {0.0f, 0.0f};

    __syncthreads();

    for (int t = 0; t < TSEQ; ++t) {
        const int rp = t & 1, wp = rp ^ 1;

        // prefetch x(t+1) early; consumed at end of this iteration
        int tn = t + 1; if (tn > TSEQ - 1) tn = TSEQ - 1;
        const float xnext = xbase[tn * FIN];

        // ================= Layer 0 =================
        f32x4 acc[2];
        {
            // A-frag: lane holds A[m=lm][k = q*8+j]
            f16x8 a0 = *reinterpret_cast<const f16x8*>(&A0[lm][q * 8]);
            f16x8 a1 = *reinterpret_cast<const f16x8*>(&A0[lm][32 + 64 * rp + q * 8]);
            f16x8 a2 = *reinterpret_cast<const f16x8*>(&A0[lm][64 + 64 * rp + q * 8]);
            #pragma unroll
            for (int tt = 0; tt < 2; ++tt) {
                f32x4 a = {bias0[tt], bias0[tt], bias0[tt], bias0[tt]};
                a = __builtin_amdgcn_mfma_f32_16x16x32_f16(a0, bw0[tt][0], a, 0, 0, 0);
                a = __builtin_amdgcn_mfma_f32_16x16x32_f16(a1, bw0[tt][1], a, 0, 0, 0);
                a = __builtin_amdgcn_mfma_f32_16x16x32_f16(a2, bw0[tt][2], a, 0, 0, 0);
                acc[tt] = a;
            }
        }
        // C-layout (m = q*4+r, col = lm) -> per-(m,d) i,f,g,o via wave-private scratch
        #pragma unroll
        for (int tt = 0; tt < 2; ++tt)
            #pragma unroll
            for (int r = 0; r < 4; ++r)
                SCR[wave][q * 4 + r][tt * 16 + lm] = acc[tt][r];
        #pragma unroll
        for (int tt = 0; tt < 2; ++tt) {
            f32x4 g4 = *reinterpret_cast<const f32x4*>(&SCR[wave][lm][tt * 16 + q * 4]);
            float ig = sigm(g4[0]), fg = sigm(g4[1]);
            float gg = tanh_fast(g4[2]), og = sigm(g4[3]);
            float c = fg * c0[tt] + ig * gg;
            c0[tt] = c;
            float h = og * tanh_fast(c);
            const int d = wave * 8 + tt * 4 + q;
            _Float16 hh = (_Float16)h;
            A1[lm][d] = hh;                      // layer-1 input for this t
            A0[lm][32 + 64 * wp + d] = hh;       // layer-0 h for t+1
        }
        __syncthreads();   // h0_t visible to all waves before L1 MFMA

        // ================= Layer 1 =================
        {
            f16x8 a0 = *reinterpret_cast<const f16x8*>(&A1[lm][q * 8]);
            f16x8 a1 = *reinterpret_cast<const f16x8*>(&A1[lm][32 + q * 8]);
            f16x8 a2 = *reinterpret_cast<const f16x8*>(&A1[lm][64 + 64 * rp + q * 8]);
            f16x8 a3 = *reinterpret_cast<const f16x8*>(&A1[lm][96 + 64 * rp + q * 8]);
            #pragma unroll
            for (int tt = 0; tt < 2; ++tt) {
                f32x4 a = {bias1[tt], bias1[tt], bias1[tt], bias1[tt]};
                a = __builtin_amdgcn_mfma_f32_16x16x32_f16(a0, bw1[tt][0], a, 0, 0, 0);
                a = __builtin_amdgcn_mfma_f32_16x16x32_f16(a1, bw1[tt][1], a, 0, 0, 0);
                a = __builtin_amdgcn_mfma_f32_16x16x32_f16(a2, bw1[tt][2], a, 0, 0, 0);
                a = __builtin_amdgcn_mfma_f32_16x16x32_f16(a3, bw1[tt][3], a, 0, 0, 0);
                acc[tt] = a;
            }
        }
        #pragma unroll
        for (int tt = 0; tt < 2; ++tt)
            #pragma unroll
            for (int r = 0; r < 4; ++r)
                SCR[wave][q * 4 + r][tt * 16 + lm] = acc[tt][r];
        #pragma unroll
        for (int tt = 0; tt < 2; ++tt) {
            f32x4 g4 = *reinterpret_cast<const f32x4*>(&SCR[wave][lm][tt * 16 + q * 4]);
            float ig = sigm(g4[0]), fg = sigm(g4[1]);
            float gg = tanh_fast(g4[2]), og = sigm(g4[3]);
            float c = fg * c1[tt] + ig * gg;
            c1[tt] = c;
            float h = og * tanh_fast(c);
            const int d = wave * 8 + tt * 4 + q;
            A1[lm][64 + 64 * wp + d] = (_Float16)h;
            if (t == TSEQ - 1) HF[lm][d] = h;    // fp32 h1 for the head
        }
        // stage x(t+1) — safe: all L0 reads of A0 x-section finished before the
        // mid-step barrier above
        A0[xrow][xcol] = (_Float16)xnext;
        __syncthreads();   // h1/x writes visible before next step's reads
    }

    // ================= Head: LayerNorm + MLP =================
    // wave w handles rows 2w and 2w+1; lane = hidden dim (64 lanes = 64 dims)
    const float lngv = ln_g[lane], lnbv = ln_b[lane];
    const float b1v = b1[lane], w2v = w2[lane];
    const float* w1row = w1 + lane * 64;
    #pragma unroll
    for (int r = 0; r < 2; ++r) {
        const int row = wave * 2 + r;
        float v  = HF[row][lane];
        float mu = wsum(v) * (1.0f / 64.0f);
        float dv = v - mu;
        float var = wsum(dv * dv) * (1.0f / 64.0f);
        float ln = dv * rsqrtf(var + 1e-5f) * lngv + lnbv;
        LNB[wave][lane] = ln;   // wave-private: in-wave LDS ordering suffices
        float s = b1v;
        #pragma unroll
        for (int dd = 0; dd < 64; ++dd)
            s = fmaf(LNB[wave][dd], w1row[dd], s);
        s = fmaxf(s, 0.0f);
        float y = wsum(s * w2v);
        if (lane == 0) out[b0 + row] = y + b2[0];
    }
}

extern "C" void kernel_launch(void* const* d_in, const int* in_sizes, int n_in,
                              void* d_out, int out_size, void* d_ws, size_t ws_size,
                              hipStream_t stream) {
    const float* x     = (const float*)d_in[0];
    const float* w_ih0 = (const float*)d_in[1];
    const float* w_hh0 = (const float*)d_in[2];
    const float* b_ih0 = (const float*)d_in[3];
    const float* b_hh0 = (const float*)d_in[4];
    const float* w_ih1 = (const float*)d_in[5];
    const float* w_hh1 = (const float*)d_in[6];
    const float* b_ih1 = (const float*)d_in[7];
    const float* b_hh1 = (const float*)d_in[8];
    const float* ln_g  = (const float*)d_in[9];
    const float* ln_b  = (const float*)d_in[10];
    const float* w1    = (const float*)d_in[11];
    const float* b1    = (const float*)d_in[12];
    const float* w2    = (const float*)d_in[13];
    const float* b2    = (const float*)d_in[14];
    lstm_fused<<<dim3(256), dim3(512), 0, stream>>>(
        x, w_ih0, w_hh0, b_ih0, b_hh0,
        w_ih1, w_hh1, b_ih1, b_hh1,
        ln_g, ln_b, w1, b1, w2, b2, (float*)d_out);
}

// Round 3
// 428.127 us; speedup vs baseline: 1.0932x; 1.0932x over previous
//
#include <hip/hip_runtime.h>

#define TSEQ 256
#define FIN  32
#define HID  64

typedef _Float16 f16x8 __attribute__((ext_vector_type(8)));
typedef float    f32x4 __attribute__((ext_vector_type(4)));

__device__ __forceinline__ float sigm(float x) {
    return __builtin_amdgcn_rcpf(1.0f + __expf(-x));
}
__device__ __forceinline__ float tanh_fast(float x) {
    float e = __expf(2.0f * x);
    return 1.0f - 2.0f * __builtin_amdgcn_rcpf(e + 1.0f);
}
__device__ __forceinline__ float wsum(float v) {
    #pragma unroll
    for (int off = 32; off > 0; off >>= 1) v += __shfl_xor(v, off, 64);
    return v;
}

// One block = 16 batch rows, 1024 threads = 16 waves, persistent over the
// whole sequence. Wave w owns gate-tile T=w (16 permuted gate rows,
// n' = 4d+type) for BOTH layers; lane (q,lm) decodes exactly one (batch=lm,
// d=w*4+q) per layer per step. Weights are the MFMA A operand (M=gates),
// activations the B operand (N=batch); C rows q*4+r deliver all four gates
// of one (batch,d) straight into the lane's 4 acc regs — no transpose LDS.
// Two barriers per step (L0 -> barrier -> L1 -> barrier), R1-proven dataflow.
__global__ __launch_bounds__(1024, 4)
void lstm_fused(const float* __restrict__ x,
                const float* __restrict__ w_ih0, const float* __restrict__ w_hh0,
                const float* __restrict__ b_ih0, const float* __restrict__ b_hh0,
                const float* __restrict__ w_ih1, const float* __restrict__ w_hh1,
                const float* __restrict__ b_ih1, const float* __restrict__ b_hh1,
                const float* __restrict__ ln_g, const float* __restrict__ ln_b,
                const float* __restrict__ w1, const float* __restrict__ b1,
                const float* __restrict__ w2, const float* __restrict__ b2,
                float* __restrict__ out)
{
    __shared__ __align__(16) _Float16 X[2][16][32];   // x_t staging, double-buffered
    __shared__ __align__(16) _Float16 H0[2][16][72];  // h0 parity buffers
    __shared__ __align__(16) _Float16 H1[2][16][72];  // h1 parity buffers
    __shared__ __align__(16) float HF[16][68];        // final h1 (fp32) for head
    __shared__ __align__(16) float LNB[16][64];       // per-wave layernorm row

    const int tid  = threadIdx.x;
    const int wave = tid >> 6;    // 0..15 = gate tile T
    const int lane = tid & 63;
    const int q    = lane >> 4;
    const int lm   = lane & 15;
    const int q8   = q * 8;
    const int b0   = blockIdx.x * 16;

    // ---- weights as A-fragments: lane holds A[m=lm][k=q*8+j] ----
    // tile rows n' = wave*16 + m;  n' = 4d + type -> original row = type*64+d
    const int np  = wave * 16 + lm;
    const int drow = np >> 2;
    const int ty   = np & 3;
    const int row  = ty * 64 + drow;
    const int dq   = wave * 4 + q;        // the d decoded by this lane

    f16x8 w0f[3], w1f[4];
    f32x4 bias0, bias1;
    {
        const float* p0 = w_ih0 + row * FIN + q8;
        const float* p1 = w_hh0 + row * HID + q8;
        const float* p2 = w_hh0 + row * HID + 32 + q8;
        const float* p3 = w_ih1 + row * HID + q8;
        const float* p4 = w_ih1 + row * HID + 32 + q8;
        const float* p5 = w_hh1 + row * HID + q8;
        const float* p6 = w_hh1 + row * HID + 32 + q8;
        #pragma unroll
        for (int j = 0; j < 8; ++j) {
            w0f[0][j] = (_Float16)p0[j];
            w0f[1][j] = (_Float16)p1[j];
            w0f[2][j] = (_Float16)p2[j];
            w1f[0][j] = (_Float16)p3[j];
            w1f[1][j] = (_Float16)p4[j];
            w1f[2][j] = (_Float16)p5[j];
            w1f[3][j] = (_Float16)p6[j];
        }
        #pragma unroll
        for (int r = 0; r < 4; ++r) {
            bias0[r] = b_ih0[r * 64 + dq] + b_hh0[r * 64 + dq];
            bias1[r] = b_ih1[r * 64 + dq] + b_hh1[r * 64 + dq];
        }
    }

    // ---- zero h state; stage x(0); prefetch x(1) ----
    for (int i = tid; i < 2 * 16 * 72; i += 1024) {
        ((_Float16*)H0)[i] = (_Float16)0.0f;
        ((_Float16*)H1)[i] = (_Float16)0.0f;
    }
    const bool xthr = tid < 512;
    const int xrow = (tid >> 5) & 15, xcol = tid & 31;
    const float* xbase = x + (size_t)(b0 + xrow) * TSEQ * FIN + xcol;
    float xw = 0.0f;
    if (xthr) {
        X[0][xrow][xcol] = (_Float16)xbase[0];
        xw = xbase[FIN];
    }
    float c0 = 0.0f, c1 = 0.0f;
    __syncthreads();

    for (int t = 0; t < TSEQ; ++t) {
        const int pt = t & 1;

        float xnew = 0.0f;
        if (xthr && t + 2 < TSEQ) xnew = xbase[(size_t)(t + 2) * FIN];

        // ---------- Phase A: layer 0, h0(t) ----------
        {
            f16x8 bx  = *reinterpret_cast<const f16x8*>(&X[pt][lm][q8]);
            f16x8 bha = *reinterpret_cast<const f16x8*>(&H0[pt ^ 1][lm][q8]);
            f16x8 bhb = *reinterpret_cast<const f16x8*>(&H0[pt ^ 1][lm][32 + q8]);
            f32x4 a = bias0;
            a = __builtin_amdgcn_mfma_f32_16x16x32_f16(w0f[0], bx,  a, 0, 0, 0);
            a = __builtin_amdgcn_mfma_f32_16x16x32_f16(w0f[1], bha, a, 0, 0, 0);
            a = __builtin_amdgcn_mfma_f32_16x16x32_f16(w0f[2], bhb, a, 0, 0, 0);
            float ig = sigm(a[0]);
            float fg = sigm(a[1]);
            float gg = tanh_fast(a[2]);
            float og = sigm(a[3]);
            c0 = fg * c0 + ig * gg;
            float h = og * tanh_fast(c0);
            H0[pt][lm][dq] = (_Float16)h;
        }
        // stage x(t+1) into off-parity buffer (disjoint from X[pt] reads)
        if (xthr && t + 1 < TSEQ) X[pt ^ 1][xrow][xcol] = (_Float16)xw;
        xw = xnew;
        __syncthreads();

        // ---------- Phase B: layer 1, h1(t) ----------
        {
            f16x8 b0a = *reinterpret_cast<const f16x8*>(&H0[pt][lm][q8]);
            f16x8 b0b = *reinterpret_cast<const f16x8*>(&H0[pt][lm][32 + q8]);
            f16x8 b1a = *reinterpret_cast<const f16x8*>(&H1[pt ^ 1][lm][q8]);
            f16x8 b1b = *reinterpret_cast<const f16x8*>(&H1[pt ^ 1][lm][32 + q8]);
            f32x4 a = bias1;
            a = __builtin_amdgcn_mfma_f32_16x16x32_f16(w1f[0], b0a, a, 0, 0, 0);
            a = __builtin_amdgcn_mfma_f32_16x16x32_f16(w1f[1], b0b, a, 0, 0, 0);
            a = __builtin_amdgcn_mfma_f32_16x16x32_f16(w1f[2], b1a, a, 0, 0, 0);
            a = __builtin_amdgcn_mfma_f32_16x16x32_f16(w1f[3], b1b, a, 0, 0, 0);
            float ig = sigm(a[0]);
            float fg = sigm(a[1]);
            float gg = tanh_fast(a[2]);
            float og = sigm(a[3]);
            c1 = fg * c1 + ig * gg;
            float h = og * tanh_fast(c1);
            H1[pt][lm][dq] = (_Float16)h;
            if (t == TSEQ - 1) HF[lm][dq] = h;
        }
        __syncthreads();
    }

    // ================= Head: LayerNorm + MLP (wave w -> batch row w) =========
    const float lngv = ln_g[lane], lnbv = ln_b[lane];
    const float b1v = b1[lane], w2v = w2[lane];
    const float* w1row = w1 + lane * 64;
    {
        float v  = HF[wave][lane];
        float mu = wsum(v) * (1.0f / 64.0f);
        float dv = v - mu;
        float var = wsum(dv * dv) * (1.0f / 64.0f);
        float ln = dv * rsqrtf(var + 1e-5f) * lngv + lnbv;
        LNB[wave][lane] = ln;   // wave-private buffer
        float s = b1v;
        #pragma unroll
        for (int dd = 0; dd < 64; ++dd)
            s = fmaf(LNB[wave][dd], w1row[dd], s);
        s = fmaxf(s, 0.0f);
        float y = wsum(s * w2v);
        if (lane == 0) out[b0 + wave] = y + b2[0];
    }
}

extern "C" void kernel_launch(void* const* d_in, const int* in_sizes, int n_in,
                              void* d_out, int out_size, void* d_ws, size_t ws_size,
                              hipStream_t stream) {
    const float* x     = (const float*)d_in[0];
    const float* w_ih0 = (const float*)d_in[1];
    const float* w_hh0 = (const float*)d_in[2];
    const float* b_ih0 = (const float*)d_in[3];
    const float* b_hh0 = (const float*)d_in[4];
    const float* w_ih1 = (const float*)d_in[5];
    const float* w_hh1 = (const float*)d_in[6];
    const float* b_ih1 = (const float*)d_in[7];
    const float* b_hh1 = (const float*)d_in[8];
    const float* ln_g  = (const float*)d_in[9];
    const float* ln_b  = (const float*)d_in[10];
    const float* w1    = (const float*)d_in[11];
    const float* b1    = (const float*)d_in[12];
    const float* w2    = (const float*)d_in[13];
    const float* b2    = (const float*)d_in[14];
    lstm_fused<<<dim3(256), dim3(1024), 0, stream>>>(
        x, w_ih0, w_hh0, b_ih0, b_hh0,
        w_ih1, w_hh1, b_ih1, b_hh1,
        ln_g, ln_b, w1, b1, w2, b2, (float*)d_out);
}

// Round 4
// 397.626 us; speedup vs baseline: 1.1771x; 1.0767x over previous
//
#include <hip/hip_runtime.h>

#define TSEQ 256
#define FIN  32
#define HID  64

typedef _Float16 f16x8 __attribute__((ext_vector_type(8)));
typedef float    f32x4 __attribute__((ext_vector_type(4)));

__device__ __forceinline__ float sigm(float x) {
    return __builtin_amdgcn_rcpf(1.0f + __expf(-x));
}
__device__ __forceinline__ float tanh_fast(float x) {
    float e = __expf(2.0f * x);
    return 1.0f - 2.0f * __builtin_amdgcn_rcpf(e + 1.0f);
}
__device__ __forceinline__ float wsum(float v) {
    #pragma unroll
    for (int off = 32; off > 0; off >>= 1) v += __shfl_xor(v, off, 64);
    return v;
}

// One block = 16 batch rows, 1024 threads = 16 waves, persistent over the
// whole sequence. Wave w owns gate-tile T=w (n' = 4d+type permutation) for
// BOTH layers; lane (q,lm) decodes one (batch=lm, d=w*4+q) per layer per
// step. Weights = MFMA A operand (registers); activations = B operand (LDS).
// R4: software-pipelined LDS reads — phase-B's H0 reads double as next
// phase-A's operands (kept in registers across the end barrier); H1 frags
// prefetched at top of phase A; X frag prefetched in phase B. Phase A has
// ZERO cold LDS reads, phase B two. Dataflow identical to R3 (proven).
__global__ __launch_bounds__(1024, 4)
void lstm_fused(const float* __restrict__ x,
                const float* __restrict__ w_ih0, const float* __restrict__ w_hh0,
                const float* __restrict__ b_ih0, const float* __restrict__ b_hh0,
                const float* __restrict__ w_ih1, const float* __restrict__ w_hh1,
                const float* __restrict__ b_ih1, const float* __restrict__ b_hh1,
                const float* __restrict__ ln_g, const float* __restrict__ ln_b,
                const float* __restrict__ w1, const float* __restrict__ b1,
                const float* __restrict__ w2, const float* __restrict__ b2,
                float* __restrict__ out)
{
    __shared__ __align__(16) _Float16 X[2][16][32];   // x_t staging, double-buffered
    __shared__ __align__(16) _Float16 H0[2][16][72];  // h0 parity buffers
    __shared__ __align__(16) _Float16 H1[2][16][72];  // h1 parity buffers
    __shared__ __align__(16) float HF[16][68];        // final h1 (fp32) for head
    __shared__ __align__(16) float LNB[16][64];       // per-wave layernorm row

    const int tid  = threadIdx.x;
    const int wave = tid >> 6;    // 0..15 = gate tile T
    const int lane = tid & 63;
    const int q    = lane >> 4;
    const int lm   = lane & 15;
    const int q8   = q * 8;
    const int b0   = blockIdx.x * 16;

    // ---- weights as A-fragments: lane holds A[m=lm][k=q*8+j] ----
    const int np   = wave * 16 + lm;
    const int drow = np >> 2;
    const int ty   = np & 3;
    const int row  = ty * 64 + drow;
    const int dq   = wave * 4 + q;        // the d decoded by this lane

    f16x8 w0f[3], w1f[4];
    f32x4 bias0, bias1;
    {
        const float* p0 = w_ih0 + row * FIN + q8;
        const float* p1 = w_hh0 + row * HID + q8;
        const float* p2 = w_hh0 + row * HID + 32 + q8;
        const float* p3 = w_ih1 + row * HID + q8;
        const float* p4 = w_ih1 + row * HID + 32 + q8;
        const float* p5 = w_hh1 + row * HID + q8;
        const float* p6 = w_hh1 + row * HID + 32 + q8;
        #pragma unroll
        for (int j = 0; j < 8; ++j) {
            w0f[0][j] = (_Float16)p0[j];
            w0f[1][j] = (_Float16)p1[j];
            w0f[2][j] = (_Float16)p2[j];
            w1f[0][j] = (_Float16)p3[j];
            w1f[1][j] = (_Float16)p4[j];
            w1f[2][j] = (_Float16)p5[j];
            w1f[3][j] = (_Float16)p6[j];
        }
        #pragma unroll
        for (int r = 0; r < 4; ++r) {
            bias0[r] = b_ih0[r * 64 + dq] + b_hh0[r * 64 + dq];
            bias1[r] = b_ih1[r * 64 + dq] + b_hh1[r * 64 + dq];
        }
    }

    // ---- zero h state; stage x(0); prefetch x(1) ----
    for (int i = tid; i < 2 * 16 * 72; i += 1024) {
        ((_Float16*)H0)[i] = (_Float16)0.0f;
        ((_Float16*)H1)[i] = (_Float16)0.0f;
    }
    const bool xthr = tid < 512;
    const int xrow = (tid >> 5) & 15, xcol = tid & 31;
    const float* xbase = x + (size_t)(b0 + xrow) * TSEQ * FIN + xcol;
    float xw = 0.0f;
    if (xthr) {
        X[0][xrow][xcol] = (_Float16)xbase[0];
        xw = xbase[FIN];
    }
    float c0 = 0.0f, c1 = 0.0f;
    __syncthreads();

    // ---- prologue: phase-A operands for t=0 (x(0); h0(-1)=0 from LDS) ----
    f16x8 bx  = *reinterpret_cast<const f16x8*>(&X[0][lm][q8]);
    f16x8 bha = *reinterpret_cast<const f16x8*>(&H0[1][lm][q8]);
    f16x8 bhb = *reinterpret_cast<const f16x8*>(&H0[1][lm][32 + q8]);

    for (int t = 0; t < TSEQ; ++t) {
        const int pt = t & 1;

        float xnew = 0.0f;
        if (xthr && t + 2 < TSEQ) xnew = xbase[(size_t)(t + 2) * FIN];

        // prefetch phase-B recurrent operands: h1(t-1), stable since end
        // barrier of t-1 (written phase B of t-1; next overwrite phase B of t+1)
        f16x8 b1a = *reinterpret_cast<const f16x8*>(&H1[pt ^ 1][lm][q8]);
        f16x8 b1b = *reinterpret_cast<const f16x8*>(&H1[pt ^ 1][lm][32 + q8]);

        // ---------- Phase A: layer 0, h0(t) — no cold LDS reads ----------
        {
            f32x4 a = bias0;
            a = __builtin_amdgcn_mfma_f32_16x16x32_f16(w0f[0], bx,  a, 0, 0, 0);
            a = __builtin_amdgcn_mfma_f32_16x16x32_f16(w0f[1], bha, a, 0, 0, 0);
            a = __builtin_amdgcn_mfma_f32_16x16x32_f16(w0f[2], bhb, a, 0, 0, 0);
            float ig = sigm(a[0]);
            float fg = sigm(a[1]);
            float gg = tanh_fast(a[2]);
            float og = sigm(a[3]);
            c0 = fg * c0 + ig * gg;
            float h = og * tanh_fast(c0);
            H0[pt][lm][dq] = (_Float16)h;
        }
        // stage x(t+1) into off-parity buffer (read next iter phase B / A)
        if (xthr && t + 1 < TSEQ) X[pt ^ 1][xrow][xcol] = (_Float16)xw;
        xw = xnew;
        __syncthreads();

        // ---------- Phase B: layer 1, h1(t) — 2 cold LDS reads ----------
        {
            f16x8 b0a = *reinterpret_cast<const f16x8*>(&H0[pt][lm][q8]);
            f16x8 b0b = *reinterpret_cast<const f16x8*>(&H0[pt][lm][32 + q8]);
            f32x4 a = bias1;
            a = __builtin_amdgcn_mfma_f32_16x16x32_f16(w1f[0], b0a, a, 0, 0, 0);
            a = __builtin_amdgcn_mfma_f32_16x16x32_f16(w1f[1], b0b, a, 0, 0, 0);
            a = __builtin_amdgcn_mfma_f32_16x16x32_f16(w1f[2], b1a, a, 0, 0, 0);
            a = __builtin_amdgcn_mfma_f32_16x16x32_f16(w1f[3], b1b, a, 0, 0, 0);
            float ig = sigm(a[0]);
            float fg = sigm(a[1]);
            float gg = tanh_fast(a[2]);
            float og = sigm(a[3]);
            c1 = fg * c1 + ig * gg;
            float h = og * tanh_fast(c1);
            H1[pt][lm][dq] = (_Float16)h;
            if (t == TSEQ - 1) HF[lm][dq] = h;
            // next phase-A operands: x(t+1) staged before the mid barrier;
            // h0(t) = exactly the H0 frags just read — keep in registers
            bx  = *reinterpret_cast<const f16x8*>(&X[pt ^ 1][lm][q8]);
            bha = b0a;
            bhb = b0b;
        }
        __syncthreads();
    }

    // ================= Head: LayerNorm + MLP (wave w -> batch row w) =========
    const float lngv = ln_g[lane], lnbv = ln_b[lane];
    const float b1v = b1[lane], w2v = w2[lane];
    const float* w1row = w1 + lane * 64;
    {
        float v  = HF[wave][lane];
        float mu = wsum(v) * (1.0f / 64.0f);
        float dv = v - mu;
        float var = wsum(dv * dv) * (1.0f / 64.0f);
        float ln = dv * rsqrtf(var + 1e-5f) * lngv + lnbv;
        LNB[wave][lane] = ln;   // wave-private buffer
        float s = b1v;
        #pragma unroll
        for (int dd = 0; dd < 64; ++dd)
            s = fmaf(LNB[wave][dd], w1row[dd], s);
        s = fmaxf(s, 0.0f);
        float y = wsum(s * w2v);
        if (lane == 0) out[b0 + wave] = y + b2[0];
    }
}

extern "C" void kernel_launch(void* const* d_in, const int* in_sizes, int n_in,
                              void* d_out, int out_size, void* d_ws, size_t ws_size,
                              hipStream_t stream) {
    const float* x     = (const float*)d_in[0];
    const float* w_ih0 = (const float*)d_in[1];
    const float* w_hh0 = (const float*)d_in[2];
    const float* b_ih0 = (const float*)d_in[3];
    const float* b_hh0 = (const float*)d_in[4];
    const float* w_ih1 = (const float*)d_in[5];
    const float* w_hh1 = (const float*)d_in[6];
    const float* b_ih1 = (const float*)d_in[7];
    const float* b_hh1 = (const float*)d_in[8];
    const float* ln_g  = (const float*)d_in[9];
    const float* ln_b  = (const float*)d_in[10];
    const float* w1    = (const float*)d_in[11];
    const float* b1    = (const float*)d_in[12];
    const float* w2    = (const float*)d_in[13];
    const float* b2    = (const float*)d_in[14];
    lstm_fused<<<dim3(256), dim3(1024), 0, stream>>>(
        x, w_ih0, w_hh0, b_ih0, b_hh0,
        w_ih1, w_hh1, b_ih1, b_hh1,
        ln_g, ln_b, w1, b1, w2, b2, (float*)d_out);
}

// Round 5
// 389.061 us; speedup vs baseline: 1.2030x; 1.0220x over previous
//
#include <hip/hip_runtime.h>

#define TSEQ 256
#define FIN  32
#define HID  64

typedef _Float16 f16x8 __attribute__((ext_vector_type(8)));
typedef float    f32x4 __attribute__((ext_vector_type(4)));

__device__ __forceinline__ float sigm(float x) {
    return __builtin_amdgcn_rcpf(1.0f + __expf(-x));
}
__device__ __forceinline__ float tanh_fast(float x) {
    float e = __expf(2.0f * x);
    return 1.0f - 2.0f * __builtin_amdgcn_rcpf(e + 1.0f);
}
__device__ __forceinline__ float wsum(float v) {
    #pragma unroll
    for (int off = 32; off > 0; off >>= 1) v += __shfl_xor(v, off, 64);
    return v;
}

// One block = 16 batch rows, 1024 threads = 16 waves, persistent.
// Wave w owns gate-tile T=w (n' = 4d+type permutation) for BOTH layers;
// lane (q,lm) decodes one (batch=lm, d=w*4+q) per layer per interval.
// R5: skew pipeline — interval i runs layer0 step i AND layer1 step i-1 in
// the same wave, ONE barrier per interval (256 total vs R4's 512). Both
// phases' operands are produced strictly before the interval's opening
// barrier (A needs x(i), h0(i-1); B needs h0(i-1), h1(i-2)), and the two
// decode chains are independent -> 2x ILP on the trans-pipe critical path.
// All X/H0/H1 read-vs-overwrite pairs are separated by exactly one barrier.
__global__ __launch_bounds__(1024, 4)
void lstm_fused(const float* __restrict__ x,
                const float* __restrict__ w_ih0, const float* __restrict__ w_hh0,
                const float* __restrict__ b_ih0, const float* __restrict__ b_hh0,
                const float* __restrict__ w_ih1, const float* __restrict__ w_hh1,
                const float* __restrict__ b_ih1, const float* __restrict__ b_hh1,
                const float* __restrict__ ln_g, const float* __restrict__ ln_b,
                const float* __restrict__ w1, const float* __restrict__ b1,
                const float* __restrict__ w2, const float* __restrict__ b2,
                float* __restrict__ out)
{
    __shared__ __align__(16) _Float16 X[2][16][32];   // x_t staging, double-buffered
    __shared__ __align__(16) _Float16 H0[2][16][72];  // h0 parity buffers
    __shared__ __align__(16) _Float16 H1[2][16][72];  // h1 parity buffers
    __shared__ __align__(16) float HF[16][68];        // final h1 (fp32) for head
    __shared__ __align__(16) float LNB[16][64];       // per-wave layernorm row

    const int tid  = threadIdx.x;
    const int wave = tid >> 6;    // 0..15 = gate tile T
    const int lane = tid & 63;
    const int q    = lane >> 4;
    const int lm   = lane & 15;
    const int q8   = q * 8;
    const int b0   = blockIdx.x * 16;

    // ---- weights as A-fragments: lane holds A[m=lm][k=q*8+j] ----
    const int np   = wave * 16 + lm;
    const int drow = np >> 2;
    const int ty   = np & 3;
    const int row  = ty * 64 + drow;
    const int dq   = wave * 4 + q;        // the d decoded by this lane

    f16x8 w0f[3], w1f[4];
    f32x4 bias0, bias1;
    {
        const float* p0 = w_ih0 + row * FIN + q8;
        const float* p1 = w_hh0 + row * HID + q8;
        const float* p2 = w_hh0 + row * HID + 32 + q8;
        const float* p3 = w_ih1 + row * HID + q8;
        const float* p4 = w_ih1 + row * HID + 32 + q8;
        const float* p5 = w_hh1 + row * HID + q8;
        const float* p6 = w_hh1 + row * HID + 32 + q8;
        #pragma unroll
        for (int j = 0; j < 8; ++j) {
            w0f[0][j] = (_Float16)p0[j];
            w0f[1][j] = (_Float16)p1[j];
            w0f[2][j] = (_Float16)p2[j];
            w1f[0][j] = (_Float16)p3[j];
            w1f[1][j] = (_Float16)p4[j];
            w1f[2][j] = (_Float16)p5[j];
            w1f[3][j] = (_Float16)p6[j];
        }
        #pragma unroll
        for (int r = 0; r < 4; ++r) {
            bias0[r] = b_ih0[r * 64 + dq] + b_hh0[r * 64 + dq];
            bias1[r] = b_ih1[r * 64 + dq] + b_hh1[r * 64 + dq];
        }
    }

    // ---- zero h state; stage x(0); prefetch x(1) ----
    for (int i = tid; i < 2 * 16 * 72; i += 1024) {
        ((_Float16*)H0)[i] = (_Float16)0.0f;
        ((_Float16*)H1)[i] = (_Float16)0.0f;
    }
    const bool xthr = tid < 512;
    const int xrow = (tid >> 5) & 15, xcol = tid & 31;
    const float* xbase = x + (size_t)(b0 + xrow) * TSEQ * FIN + xcol;
    float xw = 0.0f;
    if (xthr) {
        X[0][xrow][xcol] = (_Float16)xbase[0];
        xw = xbase[FIN];
    }
    float c0 = 0.0f, c1 = 0.0f;
    __syncthreads();

    // Interval i: phase A computes h0(i) (i<TSEQ); phase B computes h1(i-1)
    // (i>=1). Parity p = i&1. A reads X[p], H0[p^1]; writes H0[p].
    // B reads H0[p^1], H1[p]; writes H1[p^1].
    for (int i = 0; i <= TSEQ; ++i) {
        const int p = i & 1;

        float xnew = 0.0f;
        if (xthr && i + 2 < TSEQ) xnew = xbase[(size_t)(i + 2) * FIN];

        // ---- all LDS operands (stable for the whole interval) ----
        f16x8 rx   = *reinterpret_cast<const f16x8*>(&X[p][lm][q8]);
        f16x8 rh0a = *reinterpret_cast<const f16x8*>(&H0[p ^ 1][lm][q8]);
        f16x8 rh0b = *reinterpret_cast<const f16x8*>(&H0[p ^ 1][lm][32 + q8]);
        f16x8 rh1a = *reinterpret_cast<const f16x8*>(&H1[p][lm][q8]);
        f16x8 rh1b = *reinterpret_cast<const f16x8*>(&H1[p][lm][32 + q8]);

        // ---- MFMAs (A and B chains independent) ----
        f32x4 aA, aB;
        if (i < TSEQ) {
            aA = bias0;
            aA = __builtin_amdgcn_mfma_f32_16x16x32_f16(w0f[0], rx,   aA, 0, 0, 0);
            aA = __builtin_amdgcn_mfma_f32_16x16x32_f16(w0f[1], rh0a, aA, 0, 0, 0);
            aA = __builtin_amdgcn_mfma_f32_16x16x32_f16(w0f[2], rh0b, aA, 0, 0, 0);
        }
        if (i >= 1) {
            aB = bias1;
            aB = __builtin_amdgcn_mfma_f32_16x16x32_f16(w1f[0], rh0a, aB, 0, 0, 0);
            aB = __builtin_amdgcn_mfma_f32_16x16x32_f16(w1f[1], rh0b, aB, 0, 0, 0);
            aB = __builtin_amdgcn_mfma_f32_16x16x32_f16(w1f[2], rh1a, aB, 0, 0, 0);
            aB = __builtin_amdgcn_mfma_f32_16x16x32_f16(w1f[3], rh1b, aB, 0, 0, 0);
        }

        // ---- decode A: h0(i) ----
        if (i < TSEQ) {
            float ig = sigm(aA[0]);
            float fg = sigm(aA[1]);
            float gg = tanh_fast(aA[2]);
            float og = sigm(aA[3]);
            c0 = fg * c0 + ig * gg;
            float h = og * tanh_fast(c0);
            H0[p][lm][dq] = (_Float16)h;
        }
        // ---- decode B: h1(i-1) ----
        if (i >= 1) {
            float ig = sigm(aB[0]);
            float fg = sigm(aB[1]);
            float gg = tanh_fast(aB[2]);
            float og = sigm(aB[3]);
            c1 = fg * c1 + ig * gg;
            float h = og * tanh_fast(c1);
            H1[p ^ 1][lm][dq] = (_Float16)h;
            if (i == TSEQ) HF[lm][dq] = h;
        }
        // ---- stage x(i+1) into off-parity buffer ----
        if (xthr && i + 1 < TSEQ) X[p ^ 1][xrow][xcol] = (_Float16)xw;
        xw = xnew;
        __syncthreads();
    }

    // ================= Head: LayerNorm + MLP (wave w -> batch row w) =========
    const float lngv = ln_g[lane], lnbv = ln_b[lane];
    const float b1v = b1[lane], w2v = w2[lane];
    const float* w1row = w1 + lane * 64;
    {
        float v  = HF[wave][lane];
        float mu = wsum(v) * (1.0f / 64.0f);
        float dv = v - mu;
        float var = wsum(dv * dv) * (1.0f / 64.0f);
        float ln = dv * rsqrtf(var + 1e-5f) * lngv + lnbv;
        LNB[wave][lane] = ln;   // wave-private buffer
        float s = b1v;
        #pragma unroll
        for (int dd = 0; dd < 64; ++dd)
            s = fmaf(LNB[wave][dd], w1row[dd], s);
        s = fmaxf(s, 0.0f);
        float y = wsum(s * w2v);
        if (lane == 0) out[b0 + wave] = y + b2[0];
    }
}

extern "C" void kernel_launch(void* const* d_in, const int* in_sizes, int n_in,
                              void* d_out, int out_size, void* d_ws, size_t ws_size,
                              hipStream_t stream) {
    const float* x     = (const float*)d_in[0];
    const float* w_ih0 = (const float*)d_in[1];
    const float* w_hh0 = (const float*)d_in[2];
    const float* b_ih0 = (const float*)d_in[3];
    const float* b_hh0 = (const float*)d_in[4];
    const float* w_ih1 = (const float*)d_in[5];
    const float* w_hh1 = (const float*)d_in[6];
    const float* b_ih1 = (const float*)d_in[7];
    const float* b_hh1 = (const float*)d_in[8];
    const float* ln_g  = (const float*)d_in[9];
    const float* ln_b  = (const float*)d_in[10];
    const float* w1    = (const float*)d_in[11];
    const float* b1    = (const float*)d_in[12];
    const float* w2    = (const float*)d_in[13];
    const float* b2    = (const float*)d_in[14];
    lstm_fused<<<dim3(256), dim3(1024), 0, stream>>>(
        x, w_ih0, w_hh0, b_ih0, b_hh0,
        w_ih1, w_hh1, b_ih1, b_hh1,
        ln_g, ln_b, w1, b1, w2, b2, (float*)d_out);
}

// Round 6
// 370.518 us; speedup vs baseline: 1.2632x; 1.0500x over previous
//
#include <hip/hip_runtime.h>

#define TSEQ 256
#define FIN  32
#define HID  64

typedef _Float16 f16x8 __attribute__((ext_vector_type(8)));
typedef float    f32x4 __attribute__((ext_vector_type(4)));

__device__ __forceinline__ float wsum(float v) {
    #pragma unroll
    for (int off = 32; off > 0; off >>= 1) v += __shfl_xor(v, off, 64);
    return v;
}

// Merged-rcp LSTM cell: 5 exp + 3 rcp (was 5 exp + 5 rcp).
// sigma(i)*tanh(g) = (e^2g - 1) * rcp((1+e^-i)*(e^2g + 1)); same for o,tanh(c).
// c clamped to +-15 before exp for the same overflow safety as 1-2*rcp(e+1).
__device__ __forceinline__ float lstm_cell(const f32x4 g, float& c) {
    float ei = __expf(-g[0]);
    float ef = __expf(-g[1]);
    float yg = __expf(2.0f * g[2]);
    float eo = __expf(-g[3]);
    float sf = __builtin_amdgcn_rcpf(1.0f + ef);
    float ig = (yg - 1.0f) * __builtin_amdgcn_rcpf((1.0f + ei) * (yg + 1.0f));
    c = fmaf(sf, c, ig);
    float cc = fminf(fmaxf(c, -15.0f), 15.0f);
    float yc = __expf(2.0f * cc);
    return (yc - 1.0f) * __builtin_amdgcn_rcpf((1.0f + eo) * (yc + 1.0f));
}

// One block = 16 batch rows, 1024 threads = 16 waves, persistent.
// Wave w owns gate-tile T=w (n' = 4d+type permutation) for BOTH layers;
// lane (q,lm) decodes one (batch=lm, d=w*4+q) per layer per interval.
// Skew pipeline (R5-proven): interval i runs layer0 step i and layer1 step
// i-1, one barrier per interval. R6: parity-specialized macro bodies (all
// LDS addresses lane-constant, no hot-loop branches), merged-rcp decode,
// x staging spread across all 16 waves (lanes 0-31 of wave w stage row w).
__global__ __launch_bounds__(1024, 4)
void lstm_fused(const float* __restrict__ x,
                const float* __restrict__ w_ih0, const float* __restrict__ w_hh0,
                const float* __restrict__ b_ih0, const float* __restrict__ b_hh0,
                const float* __restrict__ w_ih1, const float* __restrict__ w_hh1,
                const float* __restrict__ b_ih1, const float* __restrict__ b_hh1,
                const float* __restrict__ ln_g, const float* __restrict__ ln_b,
                const float* __restrict__ w1, const float* __restrict__ b1,
                const float* __restrict__ w2, const float* __restrict__ b2,
                float* __restrict__ out)
{
    __shared__ __align__(16) _Float16 X[2][16][32];   // x_t staging, double-buffered
    __shared__ __align__(16) _Float16 H0[2][16][72];  // h0 parity buffers
    __shared__ __align__(16) _Float16 H1[2][16][72];  // h1 parity buffers
    __shared__ __align__(16) float HF[16][68];        // final h1 (fp32) for head
    __shared__ __align__(16) float LNB[16][64];       // per-wave layernorm row

    const int tid  = threadIdx.x;
    const int wave = tid >> 6;    // 0..15 = gate tile T (and x-staging row)
    const int lane = tid & 63;
    const int q    = lane >> 4;
    const int lm   = lane & 15;
    const int q8   = q * 8;
    const int b0   = blockIdx.x * 16;

    // ---- weights as A-fragments: lane holds A[m=lm][k=q*8+j] ----
    const int np   = wave * 16 + lm;
    const int drow = np >> 2;
    const int ty   = np & 3;
    const int row  = ty * 64 + drow;
    const int dq   = wave * 4 + q;        // the d decoded by this lane

    f16x8 w0f[3], w1f[4];
    f32x4 bias0, bias1;
    {
        const float* p0 = w_ih0 + row * FIN + q8;
        const float* p1 = w_hh0 + row * HID + q8;
        const float* p2 = w_hh0 + row * HID + 32 + q8;
        const float* p3 = w_ih1 + row * HID + q8;
        const float* p4 = w_ih1 + row * HID + 32 + q8;
        const float* p5 = w_hh1 + row * HID + q8;
        const float* p6 = w_hh1 + row * HID + 32 + q8;
        #pragma unroll
        for (int j = 0; j < 8; ++j) {
            w0f[0][j] = (_Float16)p0[j];
            w0f[1][j] = (_Float16)p1[j];
            w0f[2][j] = (_Float16)p2[j];
            w1f[0][j] = (_Float16)p3[j];
            w1f[1][j] = (_Float16)p4[j];
            w1f[2][j] = (_Float16)p5[j];
            w1f[3][j] = (_Float16)p6[j];
        }
        #pragma unroll
        for (int r = 0; r < 4; ++r) {
            bias0[r] = b_ih0[r * 64 + dq] + b_hh0[r * 64 + dq];
            bias1[r] = b_ih1[r * 64 + dq] + b_hh1[r * 64 + dq];
        }
    }

    // ---- zero h state ----
    for (int i = tid; i < 2 * 16 * 72; i += 1024) {
        ((_Float16*)H0)[i] = (_Float16)0.0f;
        ((_Float16*)H1)[i] = (_Float16)0.0f;
    }
    // ---- x staging: lanes 0-31 of wave w stage batch row w ----
    const bool xlane = lane < 32;
    const int  xcol  = lane & 31;
    const float* xbase = x + (size_t)(b0 + wave) * TSEQ * FIN + xcol;
    if (xlane) X[0][wave][xcol] = (_Float16)xbase[0];
    float xw = xbase[FIN];   // x(1); only lanes<32 use it

    float c0 = 0.0f, c1 = 0.0f;
    __syncthreads();

// Interval i (parity P=i&1): phase A computes h0(i): reads X[P], H0[P^1],
// writes H0[P]. Phase B computes h1(i-1): reads H0[P^1], H1[P], writes
// H1[P^1]. x: store X[P^1] <- xw (=x(i+1)), load xw <- x(XI).
#define INTERVAL(P, DO_A, DO_B, DO_XSTORE, DO_XLOAD, XI)                        \
    {                                                                           \
        float xnew = 0.0f;                                                      \
        if (DO_XLOAD) xnew = xbase[(size_t)(XI) * FIN];                         \
        f16x8 rh0a = *reinterpret_cast<const f16x8*>(&H0[(P) ^ 1][lm][q8]);     \
        f16x8 rh0b = *reinterpret_cast<const f16x8*>(&H0[(P) ^ 1][lm][32 + q8]);\
        if (DO_A) {                                                             \
            f16x8 rx = *reinterpret_cast<const f16x8*>(&X[P][lm][q8]);          \
            f32x4 aA = bias0;                                                   \
            aA = __builtin_amdgcn_mfma_f32_16x16x32_f16(w0f[0], rx,   aA, 0, 0, 0); \
            aA = __builtin_amdgcn_mfma_f32_16x16x32_f16(w0f[1], rh0a, aA, 0, 0, 0); \
            aA = __builtin_amdgcn_mfma_f32_16x16x32_f16(w0f[2], rh0b, aA, 0, 0, 0); \
            float hA = lstm_cell(aA, c0);                                       \
            H0[P][lm][dq] = (_Float16)hA;                                       \
        }                                                                       \
        if (DO_B) {                                                             \
            f16x8 rh1a = *reinterpret_cast<const f16x8*>(&H1[P][lm][q8]);       \
            f16x8 rh1b = *reinterpret_cast<const f16x8*>(&H1[P][lm][32 + q8]);  \
            f32x4 aB = bias1;                                                   \
            aB = __builtin_amdgcn_mfma_f32_16x16x32_f16(w1f[0], rh0a, aB, 0, 0, 0); \
            aB = __builtin_amdgcn_mfma_f32_16x16x32_f16(w1f[1], rh0b, aB, 0, 0, 0); \
            aB = __builtin_amdgcn_mfma_f32_16x16x32_f16(w1f[2], rh1a, aB, 0, 0, 0); \
            aB = __builtin_amdgcn_mfma_f32_16x16x32_f16(w1f[3], rh1b, aB, 0, 0, 0); \
            float hB = lstm_cell(aB, c1);                                       \
            H1[(P) ^ 1][lm][dq] = (_Float16)hB;                                 \
            lastB = hB;                                                         \
        }                                                                       \
        if (DO_XSTORE && xlane) X[(P) ^ 1][wave][xcol] = (_Float16)xw;          \
        xw = xnew;                                                              \
        __syncthreads();                                                        \
    }

    float lastB = 0.0f;

    // peel i = 0 (P=0): A only; store x(1), load x(2)
    INTERVAL(0, true, false, true, true, 2)

    // main: i = 1..254 as 127 (odd,even) pairs, fully active
    #pragma unroll 1
    for (int ii = 0; ii < 127; ++ii) {
        const int i1  = 2 * ii + 1;
        const int xiA = (i1 + 2 > 255) ? 255 : i1 + 2;
        const int xiB = (i1 + 3 > 255) ? 255 : i1 + 3;
        INTERVAL(1, true, true, true, true, xiA)
        INTERVAL(0, true, true, true, true, xiB)
    }

    // peel i = 255 (P=1): A+B, no x staging
    INTERVAL(1, true, true, false, false, 0)
    // peel i = 256 (P=0): B only -> h1(255)
    INTERVAL(0, false, true, false, false, 0)
    HF[lm][dq] = lastB;
    __syncthreads();

#undef INTERVAL

    // ================= Head: LayerNorm + MLP (wave w -> batch row w) =========
    const float lngv = ln_g[lane], lnbv = ln_b[lane];
    const float b1v = b1[lane], w2v = w2[lane];
    const float* w1row = w1 + lane * 64;
    {
        float v  = HF[wave][lane];
        float mu = wsum(v) * (1.0f / 64.0f);
        float dv = v - mu;
        float var = wsum(dv * dv) * (1.0f / 64.0f);
        float ln = dv * rsqrtf(var + 1e-5f) * lngv + lnbv;
        LNB[wave][lane] = ln;   // wave-private buffer
        float s = b1v;
        #pragma unroll
        for (int dd = 0; dd < 64; ++dd)
            s = fmaf(LNB[wave][dd], w1row[dd], s);
        s = fmaxf(s, 0.0f);
        float y = wsum(s * w2v);
        if (lane == 0) out[b0 + wave] = y + b2[0];
    }
}

extern "C" void kernel_launch(void* const* d_in, const int* in_sizes, int n_in,
                              void* d_out, int out_size, void* d_ws, size_t ws_size,
                              hipStream_t stream) {
    const float* x     = (const float*)d_in[0];
    const float* w_ih0 = (const float*)d_in[1];
    const float* w_hh0 = (const float*)d_in[2];
    const float* b_ih0 = (const float*)d_in[3];
    const float* b_hh0 = (const float*)d_in[4];
    const float* w_ih1 = (const float*)d_in[5];
    const float* w_hh1 = (const float*)d_in[6];
    const float* b_ih1 = (const float*)d_in[7];
    const float* b_hh1 = (const float*)d_in[8];
    const float* ln_g  = (const float*)d_in[9];
    const float* ln_b  = (const float*)d_in[10];
    const float* w1    = (const float*)d_in[11];
    const float* b1    = (const float*)d_in[12];
    const float* w2    = (const float*)d_in[13];
    const float* b2    = (const float*)d_in[14];
    lstm_fused<<<dim3(256), dim3(1024), 0, stream>>>(
        x, w_ih0, w_hh0, b_ih0, b_hh0,
        w_ih1, w_hh1, b_ih1, b_hh1,
        ln_g, ln_b, w1, b1, w2, b2, (float*)d_out);
}